// Round 10
// baseline (142.181 us; speedup 1.0000x reference)
//
#include <hip/hip_runtime.h>
#include <math.h>

// B=65536 rows, N=1024 cols, fp32.
//   t_b = argmax_c target[b,c]  (first-max tie-break)
//   out = mean_b(-log(y[b,t_b]+1e-8)) + sum_{b,c} w[popc(t_b^c)]*y[b,c]/(B*N), w[p]=(p==0)?0:6^p
// R8 lesson: float4 ARRAYS -> LDS/scratch (16.9KB LDS, 4.7M bank conflicts). Named
// scalars only. R9 = proven R4 body + __launch_bounds__(256,3): grant ~168 VGPR so the
// compiler can keep t(32)+y(32) float4 in flight (R4's VGPR=60 budget sank the y-loads
// behind the argmax chain -> serial stages). Atomic finish, single kernel.

#define B_ROWS 65536
#define N_COLS 1024
#define WAVES_PER_BLOCK 4
#define ROWS_BLOCKS 2048
#define ROWS_THREADS (WAVES_PER_BLOCK * 64)
#define NWAVES (ROWS_BLOCKS * WAVES_PER_BLOCK)  // 8192 waves; 8 rows/wave = 4 iters x 2 rows

__global__ __launch_bounds__(ROWS_THREADS, 3)
void ce_rows_kernel(const float* __restrict__ y_true,
                    const float* __restrict__ target,
                    float* __restrict__ out) {
    __shared__ float w_lds[16];
    __shared__ float wave_part[WAVES_PER_BLOCK];

    const int tid = threadIdx.x;
    if (tid < 16) {
        float w = 1.0f;
        for (int p = 0; p < tid; ++p) w *= 6.0f;   // exact: 6^10 < 2^26
        w_lds[tid] = (tid == 0) ? 0.0f : w;
    }
    __syncthreads();

    const int lane  = tid & 63;
    const int wid   = tid >> 6;
    const int gwave = blockIdx.x * WAVES_PER_BLOCK + wid;

    float acc_pt = 0.0f;   // lane-private weighted-sum partial
    float acc_lg = 0.0f;   // lane-private sum of log(y[t]+1e-8), owner lanes only

    #pragma unroll 1
    for (int it = 0; it < 4; ++it) {
        const int rowA = gwave + (2 * it)     * NWAVES;
        const int rowB = gwave + (2 * it + 1) * NWAVES;
        const float4* tA = (const float4*)(target + (size_t)rowA * N_COLS);
        const float4* tB = (const float4*)(target + (size_t)rowB * N_COLS);
        const float4* yA = (const float4*)(y_true + (size_t)rowA * N_COLS);
        const float4* yB = (const float4*)(y_true + (size_t)rowB * N_COLS);

        // issue all 16 coalesced float4 loads up front (named scalars, no arrays)
        float4 ta0 = tA[lane], ta1 = tA[lane + 64], ta2 = tA[lane + 128], ta3 = tA[lane + 192];
        float4 tb0 = tB[lane], tb1 = tB[lane + 64], tb2 = tB[lane + 128], tb3 = tB[lane + 192];
        float4 ya0 = yA[lane], ya1 = yA[lane + 64], ya2 = yA[lane + 128], ya3 = yA[lane + 192];
        float4 yb0 = yB[lane], yb1 = yB[lane + 64], yb2 = yB[lane + 128], yb3 = yB[lane + 192];

        // local argmax, two independent chains; strict > on ascending scan = first-index
        float bvA = -1.0f, bvB = -1.0f;
        int   biA = 0,     biB = 0;
        const int c0 = 4 * lane, c1 = 4 * (lane + 64), c2 = 4 * (lane + 128), c3 = 4 * (lane + 192);
        if (ta0.x > bvA) { bvA = ta0.x; biA = c0;     }
        if (ta0.y > bvA) { bvA = ta0.y; biA = c0 + 1; }
        if (ta0.z > bvA) { bvA = ta0.z; biA = c0 + 2; }
        if (ta0.w > bvA) { bvA = ta0.w; biA = c0 + 3; }
        if (ta1.x > bvA) { bvA = ta1.x; biA = c1;     }
        if (ta1.y > bvA) { bvA = ta1.y; biA = c1 + 1; }
        if (ta1.z > bvA) { bvA = ta1.z; biA = c1 + 2; }
        if (ta1.w > bvA) { bvA = ta1.w; biA = c1 + 3; }
        if (ta2.x > bvA) { bvA = ta2.x; biA = c2;     }
        if (ta2.y > bvA) { bvA = ta2.y; biA = c2 + 1; }
        if (ta2.z > bvA) { bvA = ta2.z; biA = c2 + 2; }
        if (ta2.w > bvA) { bvA = ta2.w; biA = c2 + 3; }
        if (ta3.x > bvA) { bvA = ta3.x; biA = c3;     }
        if (ta3.y > bvA) { bvA = ta3.y; biA = c3 + 1; }
        if (ta3.z > bvA) { bvA = ta3.z; biA = c3 + 2; }
        if (ta3.w > bvA) { bvA = ta3.w; biA = c3 + 3; }
        if (tb0.x > bvB) { bvB = tb0.x; biB = c0;     }
        if (tb0.y > bvB) { bvB = tb0.y; biB = c0 + 1; }
        if (tb0.z > bvB) { bvB = tb0.z; biB = c0 + 2; }
        if (tb0.w > bvB) { bvB = tb0.w; biB = c0 + 3; }
        if (tb1.x > bvB) { bvB = tb1.x; biB = c1;     }
        if (tb1.y > bvB) { bvB = tb1.y; biB = c1 + 1; }
        if (tb1.z > bvB) { bvB = tb1.z; biB = c1 + 2; }
        if (tb1.w > bvB) { bvB = tb1.w; biB = c1 + 3; }
        if (tb2.x > bvB) { bvB = tb2.x; biB = c2;     }
        if (tb2.y > bvB) { bvB = tb2.y; biB = c2 + 1; }
        if (tb2.z > bvB) { bvB = tb2.z; biB = c2 + 2; }
        if (tb2.w > bvB) { bvB = tb2.w; biB = c2 + 3; }
        if (tb3.x > bvB) { bvB = tb3.x; biB = c3;     }
        if (tb3.y > bvB) { bvB = tb3.y; biB = c3 + 1; }
        if (tb3.z > bvB) { bvB = tb3.z; biB = c3 + 2; }
        if (tb3.w > bvB) { bvB = tb3.w; biB = c3 + 3; }

        // cross-lane argmax with first-index tie-break; A and B chains interleave
        #pragma unroll
        for (int m = 32; m >= 1; m >>= 1) {
            float ovA = __shfl_xor(bvA, m, 64); int oiA = __shfl_xor(biA, m, 64);
            if (ovA > bvA || (ovA == bvA && oiA < biA)) { bvA = ovA; biA = oiA; }
            float ovB = __shfl_xor(bvB, m, 64); int oiB = __shfl_xor(biB, m, 64);
            if (ovB > bvB || (ovB == bvB && oiB < biB)) { bvB = ovB; biB = oiB; }
        }
        const int tAi = biA;   // wave-uniform
        const int tBi = biB;

        // weighted sums: lane-private, no per-row reduction (popc(t^t)=0 -> w=0)
        const int xA0 = tAi ^ c0, xA1 = tAi ^ c1, xA2 = tAi ^ c2, xA3 = tAi ^ c3;
        const int xB0 = tBi ^ c0, xB1 = tBi ^ c1, xB2 = tBi ^ c2, xB3 = tBi ^ c3;
        acc_pt += w_lds[__popc(xA0)]     * ya0.x + w_lds[__popc(xA0 ^ 1)] * ya0.y
                + w_lds[__popc(xA0 ^ 2)] * ya0.z + w_lds[__popc(xA0 ^ 3)] * ya0.w
                + w_lds[__popc(xA1)]     * ya1.x + w_lds[__popc(xA1 ^ 1)] * ya1.y
                + w_lds[__popc(xA1 ^ 2)] * ya1.z + w_lds[__popc(xA1 ^ 3)] * ya1.w
                + w_lds[__popc(xA2)]     * ya2.x + w_lds[__popc(xA2 ^ 1)] * ya2.y
                + w_lds[__popc(xA2 ^ 2)] * ya2.z + w_lds[__popc(xA2 ^ 3)] * ya2.w
                + w_lds[__popc(xA3)]     * ya3.x + w_lds[__popc(xA3 ^ 1)] * ya3.y
                + w_lds[__popc(xA3 ^ 2)] * ya3.z + w_lds[__popc(xA3 ^ 3)] * ya3.w
                + w_lds[__popc(xB0)]     * yb0.x + w_lds[__popc(xB0 ^ 1)] * yb0.y
                + w_lds[__popc(xB0 ^ 2)] * yb0.z + w_lds[__popc(xB0 ^ 3)] * yb0.w
                + w_lds[__popc(xB1)]     * yb1.x + w_lds[__popc(xB1 ^ 1)] * yb1.y
                + w_lds[__popc(xB1 ^ 2)] * yb1.z + w_lds[__popc(xB1 ^ 3)] * yb1.w
                + w_lds[__popc(xB2)]     * yb2.x + w_lds[__popc(xB2 ^ 1)] * yb2.y
                + w_lds[__popc(xB2 ^ 2)] * yb2.z + w_lds[__popc(xB2 ^ 3)] * yb2.w
                + w_lds[__popc(xB3)]     * yb3.x + w_lds[__popc(xB3 ^ 1)] * yb3.y
                + w_lds[__popc(xB3 ^ 2)] * yb3.z + w_lds[__popc(xB3 ^ 3)] * yb3.w;

        // CE term: owner lane selects its element with named scalars (no array decay)
        if (((tAi >> 2) & 63) == lane) {
            const int k = tAi >> 8, e = tAi & 3;
            float4 s = (k & 2) ? ((k & 1) ? ya3 : ya2) : ((k & 1) ? ya1 : ya0);
            const float yt = (e & 2) ? ((e & 1) ? s.w : s.z) : ((e & 1) ? s.y : s.x);
            acc_lg += logf(yt + 1e-8f);
        }
        if (((tBi >> 2) & 63) == lane) {
            const int k = tBi >> 8, e = tBi & 3;
            float4 s = (k & 2) ? ((k & 1) ? yb3 : yb2) : ((k & 1) ? yb1 : yb0);
            const float yt = (e & 2) ? ((e & 1) ? s.w : s.z) : ((e & 1) ? s.y : s.x);
            acc_lg += logf(yt + 1e-8f);
        }
    }

    // single per-wave reduction at the end
    const float invB  = 1.0f / (float)B_ROWS;
    const float invBN = 1.0f / ((float)B_ROWS * (float)N_COLS);
    float val = acc_pt * invBN - acc_lg * invB;
    #pragma unroll
    for (int m = 32; m >= 1; m >>= 1) val += __shfl_xor(val, m, 64);

    if (lane == 0) wave_part[wid] = val;
    __syncthreads();
    if (tid == 0) {
        float s = 0.0f;
        #pragma unroll
        for (int w = 0; w < WAVES_PER_BLOCK; ++w) s += wave_part[w];
        atomicAdd(out, s);   // 2048 adds; reorder noise ~1e-3 << threshold 2764
    }
}

extern "C" void kernel_launch(void* const* d_in, const int* in_sizes, int n_in,
                              void* d_out, int out_size, void* d_ws, size_t ws_size,
                              hipStream_t stream) {
    const float* y_true = (const float*)d_in[0];
    const float* target = (const float*)d_in[1];
    float* out = (float*)d_out;

    hipMemsetAsync(out, 0, sizeof(float), stream);
    ce_rows_kernel<<<ROWS_BLOCKS, ROWS_THREADS, 0, stream>>>(y_true, target, out);
}